// Round 18
// baseline (111.101 us; speedup 1.0000x reference)
//
#include <hip/hip_runtime.h>
#include <math.h>

// Self-attention: B=4, S=2048, E=1024, D=512, fp32 in/out, bf16 MFMA internally.
// R18: T5 s_setprio(1) around the MFMA cluster in BOTH mainloops (single
//      uniform change vs R17). Our counted-vmcnt single-barrier schedule has
//      the wave role-split T5 needs (stage-issuing vs MFMA-entering waves at
//      2-3 blocks/CU). If neutral, schedule is not arbitration-limited.

typedef __attribute__((ext_vector_type(4))) float f32x4;
typedef __attribute__((ext_vector_type(16))) float f32x16;
typedef __attribute__((ext_vector_type(8))) short bf16x8;     // 8 bf16 = 4 VGPRs
typedef __attribute__((ext_vector_type(8))) unsigned short u16x8;

#define B_ 4
#define S_ 2048
#define E_ 1024
#define D_ 512

__device__ __forceinline__ unsigned short f2bf(float f) {
  unsigned u = __float_as_uint(f);
  u += 0x7fffu + ((u >> 16) & 1u);   // round-to-nearest-even
  return (unsigned short)(u >> 16);
}

__device__ __forceinline__ float bf2f(unsigned short h) {
  return __uint_as_float(((unsigned)h) << 16);
}

template<int N> __device__ __forceinline__ void wait_vm() {
  if constexpr (N == 0)      asm volatile("s_waitcnt vmcnt(0)" ::: "memory");
  else if constexpr (N == 3) asm volatile("s_waitcnt vmcnt(3)" ::: "memory");
  else if constexpr (N == 4) asm volatile("s_waitcnt vmcnt(4)" ::: "memory");
  else if constexpr (N == 6) asm volatile("s_waitcnt vmcnt(6)" ::: "memory");
  else static_assert(N != N, "unsupported vmcnt");
}

// ---- BK=32 staged GEMM core (qkv) ----
// LDS tile ROWS x 32 bf16; 16B granule g of row r at slot g ^ ((r>>1)&3).

template<int ROWS, int NTHR>
__device__ __forceinline__ void stage_tile32(const unsigned short* __restrict__ g, long ld,
                                             long rowBase, int kBase,
                                             unsigned short* lds, int tid) {
  constexpr int CALLS = (ROWS * 64) / (NTHR * 16);
  #pragma unroll
  for (int i = 0; i < CALLS; ++i) {
    int idx = i * NTHR + tid;
    int row = idx >> 2, cc = idx & 3;
    int src_g = cc ^ ((row >> 1) & 3);          // pre-swizzled global granule
    __builtin_amdgcn_global_load_lds(
      (const __attribute__((address_space(1))) void*)(g + (rowBase + row) * ld + kBase + src_g * 8),
      (__attribute__((address_space(3))) void*)(lds + idx * 8),
      16, 0, 0);
  }
}

// A frag for 32x32x16: lane reads A[row = lane&31][k = (lane>>5)*8 + 0..7].
template<int MT, int NTT>
__device__ __forceinline__ void compute_tile32(const unsigned short* As, const unsigned short* Bs,
                                               int a_row0, int b_row0, int lane,
                                               f32x16 (&acc)[MT][NTT]) {
  int lr = lane & 31, lhalf = lane >> 5;
  int p = (lr >> 1) & 3;                        // (row>>1)&3 with row0 % 32 == 0
  #pragma unroll
  for (int ki = 0; ki < 2; ++ki) {
    int slot = ((ki * 2 + lhalf) ^ p) * 8;      // swizzled granule offset (halfwords)
    bf16x8 af[MT], bf[NTT];
    #pragma unroll
    for (int mt = 0; mt < MT; ++mt)
      af[mt] = *(const bf16x8*)(As + (a_row0 + mt * 32 + lr) * 32 + slot);
    #pragma unroll
    for (int nt = 0; nt < NTT; ++nt)
      bf[nt] = *(const bf16x8*)(Bs + (b_row0 + nt * 32 + lr) * 32 + slot);
    __builtin_amdgcn_s_setprio(1);
    #pragma unroll
    for (int mt = 0; mt < MT; ++mt)
      #pragma unroll
      for (int nt = 0; nt < NTT; ++nt)
        acc[mt][nt] = __builtin_amdgcn_mfma_f32_32x32x16_bf16(af[mt], bf[nt], acc[mt][nt], 0, 0, 0);
    __builtin_amdgcn_s_setprio(0);
  }
}

// 3-buffer pipeline, one barrier per K-step, counted vmcnt (never 0 in-loop).
template<int AROWS, int BROWS, int NTHR, int MT, int NTT>
__device__ __forceinline__ void mainloop32(
    const unsigned short* __restrict__ A, long lda, long rowA,
    const unsigned short* __restrict__ Bt, long ldb, long rowB,
    int nsteps, unsigned short* AsBuf, unsigned short* BsBuf,
    int tid, int lane, int a_row0, int b_row0, f32x16 (&acc)[MT][NTT]) {
  constexpr int ASZ = AROWS * 32, BSZ = BROWS * 32;
  constexpr int LPS = (AROWS * 64) / (NTHR * 16) + (BROWS * 64) / (NTHR * 16);
  unsigned short *a0 = AsBuf, *a1 = AsBuf + ASZ, *a2 = AsBuf + 2 * ASZ;
  unsigned short *b0 = BsBuf, *b1 = BsBuf + BSZ, *b2 = BsBuf + 2 * BSZ;
  stage_tile32<AROWS, NTHR>(A, lda, rowA, 0, a0, tid);
  stage_tile32<BROWS, NTHR>(Bt, ldb, rowB, 0, b0, tid);
  if (nsteps > 1) {
    stage_tile32<AROWS, NTHR>(A, lda, rowA, 32, a1, tid);
    stage_tile32<BROWS, NTHR>(Bt, ldb, rowB, 32, b1, tid);
  }
  for (int t = 0; t < nsteps; ++t) {
    if (t < nsteps - 1) wait_vm<LPS>(); else wait_vm<0>();
    __builtin_amdgcn_s_barrier();
    __builtin_amdgcn_sched_barrier(0);
    compute_tile32<MT, NTT>(a0, b0, a_row0, b_row0, lane, acc);
    if (t + 2 < nsteps) {
      stage_tile32<AROWS, NTHR>(A, lda, rowA, (t + 2) * 32, a2, tid);
      stage_tile32<BROWS, NTHR>(Bt, ldb, rowB, (t + 2) * 32, b2, tid);
    }
    unsigned short* ta = a0; a0 = a1; a1 = a2; a2 = ta;
    unsigned short* tb = b0; b0 = b1; b1 = b2; b2 = tb;
  }
}

// ---- BK=64 machinery (scores, pv): ROWS x 64 bf16 tiles, slot = g ^ (row&7) ----

template<int ROWS, int NTHR>
__device__ __forceinline__ void stage_tile64(const unsigned short* __restrict__ g, long ld,
                                             long rowBase, int kBase,
                                             unsigned short* lds, int tid) {
  constexpr int CALLS = (ROWS * 128) / (NTHR * 16);
  #pragma unroll
  for (int i = 0; i < CALLS; ++i) {
    int idx = i * NTHR + tid;
    int row = idx >> 3, cc = idx & 7;
    int src_g = cc ^ (row & 7);                 // pre-swizzled global granule
    __builtin_amdgcn_global_load_lds(
      (const __attribute__((address_space(1))) void*)(g + (rowBase + row) * ld + kBase + src_g * 8),
      (__attribute__((address_space(3))) void*)(lds + idx * 8),
      16, 0, 0);
  }
}

// 64x128 tile, wave (wm,wn) does 32m x 64n, BK=64 (ki=0..3); optional
// accl = MFMA(A-frag, ones) row-sum accumulation (pv's l).
template<bool WITH_L>
__device__ __forceinline__ void compute64(const unsigned short* As, const unsigned short* Bs,
                                          int a_row0, int b_row0, int lane, bf16x8 ones,
                                          f32x16 (&acc)[2], f32x16& accl) {
  int lr = lane & 31, lhalf = lane >> 5;
  int p = lr & 7;
  #pragma unroll
  for (int ki = 0; ki < 4; ++ki) {
    int slot = ((ki * 2 + lhalf) ^ p) * 8;      // granule within 64-col row
    bf16x8 af  = *(const bf16x8*)(As + (a_row0 + lr) * 64 + slot);
    bf16x8 bf0 = *(const bf16x8*)(Bs + (b_row0 + lr) * 64 + slot);
    bf16x8 bf1 = *(const bf16x8*)(Bs + (b_row0 + 32 + lr) * 64 + slot);
    __builtin_amdgcn_s_setprio(1);
    if constexpr (WITH_L)
      accl = __builtin_amdgcn_mfma_f32_32x32x16_bf16(af, ones, accl, 0, 0, 0);
    acc[0] = __builtin_amdgcn_mfma_f32_32x32x16_bf16(af, bf0, acc[0], 0, 0, 0);
    acc[1] = __builtin_amdgcn_mfma_f32_32x32x16_bf16(af, bf1, acc[1], 0, 0, 0);
    __builtin_amdgcn_s_setprio(0);
  }
}

// 3 buffers, BK=64, LPS = 2(A) + 4(B) = 6, counted vmcnt (never 0 in-loop).
template<bool WITH_L>
__device__ __forceinline__ void mainloop64(
    const unsigned short* __restrict__ A, long lda, long rowA,
    const unsigned short* __restrict__ Bt, long ldb, long rowB,
    int nsteps, unsigned short (*As)[64 * 64], unsigned short (*Bs)[128 * 64],
    int tid, int lane, int a_row0, int b_row0,
    f32x16 (&acc)[2], f32x16& accl) {
  bf16x8 ones;
  #pragma unroll
  for (int j = 0; j < 8; ++j) ones[j] = (short)0x3F80;   // bf16 1.0
  stage_tile64<64, 256>(A, lda, rowA, 0, As[0], tid);
  stage_tile64<128, 256>(Bt, ldb, rowB, 0, Bs[0], tid);
  if (nsteps > 1) {
    stage_tile64<64, 256>(A, lda, rowA, 64, As[1], tid);
    stage_tile64<128, 256>(Bt, ldb, rowB, 64, Bs[1], tid);
  }
  int cur = 0;
  for (int t = 0; t < nsteps; ++t) {
    if (t < nsteps - 1) wait_vm<6>(); else wait_vm<0>();
    __builtin_amdgcn_s_barrier();
    __builtin_amdgcn_sched_barrier(0);
    compute64<WITH_L>(As[cur], Bs[cur], a_row0, b_row0, lane, ones, acc, accl);
    if (t + 2 < nsteps) {
      int nxt = (cur + 2) % 3;
      stage_tile64<64, 256>(A, lda, rowA, (t + 2) * 64, As[nxt], tid);
      stage_tile64<128, 256>(Bt, ldb, rowB, (t + 2) * 64, Bs[nxt], tid);
    }
    cur = (cur + 1) % 3;
  }
}

// ---- kernels ----

// part 1 (blocks [0,4096)): x f32 -> xb bf16, coalesced.
// part 2 (blocks [4096,4480)): wbT[n][k] = w[k][d] via 64x64 LDS transpose.
__global__ __launch_bounds__(256) void prep(const float* __restrict__ x,
                                            const float* __restrict__ wq,
                                            const float* __restrict__ wk,
                                            const float* __restrict__ wv,
                                            unsigned short* __restrict__ xb,
                                            unsigned short* __restrict__ wbT) {
  int bx = blockIdx.x;
  if (bx < 4096) {
    long i = (long)bx * 256 + threadIdx.x;  // 8 elems per thread
    f32x4 a = ((const f32x4*)x)[2 * i];
    f32x4 b = ((const f32x4*)x)[2 * i + 1];
    u16x8 o;
    #pragma unroll
    for (int j = 0; j < 4; ++j) { o[j] = f2bf(a[j]); o[4 + j] = f2bf(b[j]); }
    ((u16x8*)xb)[i] = o;
  } else {
    int t = bx - 4096;              // 0..383 = 3 w x 16 kblk x 8 dblk
    int widx = t >> 7;
    int rem  = t & 127;
    int kblk = rem >> 3, dblk = rem & 7;
    const float* w = (widx == 0) ? wq : ((widx == 1) ? wk : wv);
    __shared__ float ls[64][65];    // pad 65: transpose reads 2-way max
    int tid = threadIdx.x;
    int r = tid >> 2, c16 = (tid & 3) * 16;
    const float* src = w + (long)(kblk * 64 + r) * 512 + dblk * 64 + c16;
    #pragma unroll
    for (int j = 0; j < 4; ++j) {
      f32x4 v = *(const f32x4*)(src + j * 4);
      ls[r][c16 + j * 4 + 0] = v[0];
      ls[r][c16 + j * 4 + 1] = v[1];
      ls[r][c16 + j * 4 + 2] = v[2];
      ls[r][c16 + j * 4 + 3] = v[3];
    }
    __syncthreads();
    int nl = tid >> 2;              // local n (= d) row 0..63
    unsigned short* dst = wbT + (long)(widx * 512 + dblk * 64 + nl) * 1024
                              + kblk * 64 + c16;
    u16x8 o0, o1;
    #pragma unroll
    for (int j = 0; j < 8; ++j) {
      o0[j] = f2bf(ls[c16 + j][nl]);
      o1[j] = f2bf(ls[c16 + 8 + j][nl]);
    }
    *(u16x8*)dst = o0;
    *(u16x8*)(dst + 8) = o1;
  }
}

__global__ __launch_bounds__(256, 3) void qkv_gemm(
    const unsigned short* __restrict__ xb, const unsigned short* __restrict__ wbT,
    const float* __restrict__ bq, const float* __restrict__ bk, const float* __restrict__ bv,
    unsigned short* __restrict__ qb, unsigned short* __restrict__ kb,
    unsigned short* __restrict__ vtb) {
  __shared__ unsigned short lds[24576];   // 48 KB: A bufs [0,12288), B bufs [12288,24576)
  unsigned short* AsB = lds;
  unsigned short* BsB = lds + 3 * 4096;
  int tid = threadIdx.x, wave = tid >> 6, lane = tid & 63;
  int wm = wave >> 1, wn = wave & 1;
  // XCD-aware bijective swizzle: 768 wgs, 96 per XCD chunk (768 % 8 == 0).
  int wg = blockIdx.x;
  int swz = (wg & 7) * 96 + (wg >> 3);
  int nb = swz % 12, mb = swz / 12;                // n fastest -> chunk shares A panel
  long rowA = (long)mb * 128, rowB = (long)nb * 128;
  f32x16 acc[2][2] = {};
  mainloop32<128, 128, 256, 2, 2>(xb, E_, rowA, wbT, E_, rowB, E_ / 32,
                                  AsB, BsB, tid, lane, wm * 64, wn * 64, acc);
  int lc = lane & 31, lhi = (lane >> 5) * 4;
  if (rowB < 1024) {
    // q / k panels: direct [m][d] bf16 store with bias.
    #pragma unroll
    for (int nt = 0; nt < 2; ++nt) {
      int n = (int)rowB + wn * 64 + nt * 32 + lc;
      int d = n & 511;
      float bias; unsigned short* dst;
      if (n < 512) { bias = bq[d]; dst = qb; }
      else         { bias = bk[d]; dst = kb; }
      #pragma unroll
      for (int mt = 0; mt < 2; ++mt) {
        long mbase = rowA + wm * 64 + mt * 32 + lhi;
        #pragma unroll
        for (int r = 0; r < 16; ++r) {
          long m = mbase + (r & 3) + 8 * (r >> 2);
          dst[m * D_ + d] = f2bf(acc[mt][nt][r] + bias);
        }
      }
    }
  } else {
    // v panel: bias + IN-BLOCK TRANSPOSE through LDS -> vtb[d][m] coalesced.
    __syncthreads();                       // mainloop LDS reads done
    #pragma unroll
    for (int nt = 0; nt < 2; ++nt) {
      int n_loc = wn * 64 + nt * 32 + lc;
      float bias = bv[(int)(rowB - 1024) + n_loc];
      #pragma unroll
      for (int mt = 0; mt < 2; ++mt) {
        int mb0 = wm * 64 + mt * 32 + lhi;
        #pragma unroll
        for (int r = 0; r < 16; ++r) {
          int m_loc = mb0 + (r & 3) + 8 * (r >> 2);
          lds[n_loc * 136 + m_loc] = f2bf(acc[mt][nt][r] + bias);  // pad 136 vs conflicts
        }
      }
    }
    __syncthreads();
    int d_loc = tid >> 1, hf = tid & 1;    // 128 d-rows x 2 halves of 64 m
    long d = (rowB - 1024) + d_loc;
    long bb = rowA >> 11;                  // batch (rowA is 128-aligned within 2048-blocks)
    long s0 = (rowA & 2047) + hf * 64;
    unsigned short* dstv = vtb + (bb * D_ + d) * (long)S_ + s0;
    #pragma unroll
    for (int j = 0; j < 8; ++j)
      *(u16x8*)(dstv + j * 8) = *(const u16x8*)&lds[d_loc * 136 + hf * 64 + j * 8];
  }
}

// scores+exp: 64x128 tiles on the BK=64 mainloop (8 fat steps, 3-buf,
// counted vmcnt(6), 72KB LDS, 2 blocks/CU). grid (jb=16, 32, b=4), im=31-y,
// active iff 2*jb <= im (1088 blocks). Epilogue: p = exp2(s*c) masked, bf16.
__global__ __launch_bounds__(256, 2) void scores_gemm(
    const unsigned short* __restrict__ qb, const unsigned short* __restrict__ kb,
    unsigned short* __restrict__ sc) {
  int jb = blockIdx.x, im = 31 - blockIdx.y, b = blockIdx.z;
  if (2 * jb > im) return;   // tile entirely above diagonal: never read downstream
  __shared__ unsigned short As[3][64 * 64], Bs[3][128 * 64];   // 72 KB
  int tid = threadIdx.x, wave = tid >> 6, lane = tid & 63;
  int wm = wave >> 1, wn = wave & 1;   // wave-tile 32m x 64n
  const unsigned short* A  = qb + (long)b * S_ * D_;
  const unsigned short* Bt = kb + (long)b * S_ * D_;   // k stored [s][d] == [n][k]
  long rowA = (long)im * 64, rowB = (long)jb * 128;
  f32x16 acc[2] = {};
  f32x16 accl = {};
  mainloop64<false>(A, D_, rowA, Bt, D_, rowB, D_ / 64, As, Bs, tid, lane,
                    wm * 32, wn * 64, acc, accl);
  unsigned short* po = sc + (long)b * S_ * S_;
  const float cexp = 1.4426950408889634f / 22.627416997969522f;  // log2(e)/sqrt(512)
  int lc = lane & 31, lhi = (lane >> 5) * 4;
  long mbase = rowA + wm * 32 + lhi;
  #pragma unroll
  for (int r = 0; r < 16; ++r) {
    long m = mbase + (r & 3) + 8 * (r >> 2);
    #pragma unroll
    for (int nt = 0; nt < 2; ++nt) {
      long n = rowB + wn * 64 + nt * 32 + lc;
      float p = (n <= m) ? exp2f(acc[nt][r] * cexp) : 0.f;
      po[m * S_ + n] = f2bf(p);
    }
  }
}

// PV: 64x128 tile, BK=64, chain nsteps = bm+1 <= 32, 72KB LDS -> 2 blocks/CU,
// grid (bn=4, bm=32 reversed, b=4) = 512 blocks, longest-first. l via
// ones-MFMA (accl[r]); divide on store.
__global__ __launch_bounds__(256, 2) void pv_gemm(
    const unsigned short* __restrict__ sc, const unsigned short* __restrict__ vtb,
    float* __restrict__ out) {
  int bn = blockIdx.x, bm = 31 - blockIdx.y, b = blockIdx.z;
  __shared__ unsigned short As[3][64 * 64], Bs[3][128 * 64];   // 72 KB
  int tid = threadIdx.x, wave = tid >> 6, lane = tid & 63;
  int wm = wave >> 1, wn = wave & 1;   // wave-tile 32m x 64n
  const unsigned short* A  = sc  + (long)b * S_ * S_;   // P [2048][2048]
  const unsigned short* Bt = vtb + (long)b * D_ * S_;   // V^T [512][2048]
  long rowA = (long)bm * 64, rowB = (long)bn * 128;
  int nsteps = bm + 1;
  f32x16 acc[2] = {};
  f32x16 accl = {};
  mainloop64<true>(A, S_, rowA, Bt, S_, rowB, nsteps, As, Bs, tid, lane,
                   wm * 32, wn * 64, acc, accl);
  float* oo = out + (long)b * S_ * D_;
  int lc = lane & 31, lhi = (lane >> 5) * 4;
  long mbase = rowA + wm * 32 + lhi;
  #pragma unroll
  for (int r = 0; r < 16; ++r) {
    long m = mbase + (r & 3) + 8 * (r >> 2);
    float inv = 1.f / accl[r];
    #pragma unroll
    for (int nt = 0; nt < 2; ++nt) {
      long n = rowB + wn * 64 + nt * 32 + lc;
      oo[m * D_ + n] = acc[nt][r] * inv;
    }
  }
}

extern "C" void kernel_launch(void* const* d_in, const int* in_sizes, int n_in,
                              void* d_out, int out_size, void* d_ws, size_t ws_size,
                              hipStream_t stream) {
  const float* x   = (const float*)d_in[0];
  const float* wq  = (const float*)d_in[1];
  const float* bq  = (const float*)d_in[2];
  const float* wk  = (const float*)d_in[3];
  const float* bk  = (const float*)d_in[4];
  const float* wv  = (const float*)d_in[5];
  const float* bv  = (const float*)d_in[6];
  float* out = (float*)d_out;

  // workspace layout (bytes), total ~75 MB
  char* ws = (char*)d_ws;
  unsigned short* xb  = (unsigned short*)(ws);                 // 16,777,216  x bf16 [8192][1024]
  unsigned short* wbT = (unsigned short*)(ws + 16777216);      //  3,145,728  w^T bf16 [1536][1024]
  unsigned short* qb  = (unsigned short*)(ws + 19922944);      //  8,388,608  q bf16 [8192][512]
  unsigned short* kb  = (unsigned short*)(ws + 28311552);      //  8,388,608
  unsigned short* vtb = (unsigned short*)(ws + 36700160);      //  8,388,608  v^T bf16 [4][512][2048]
  unsigned short* sc  = (unsigned short*)(ws + 45088768);      // 33,554,432  p bf16 [4][2048][2048]

  prep<<<dim3(4480), dim3(256), 0, stream>>>(x, wq, wk, wv, xb, wbT);
  qkv_gemm<<<dim3(768), dim3(256), 0, stream>>>(xb, wbT, bq, bk, bv, qb, kb, vtb);
  scores_gemm<<<dim3(16, 32, 4), dim3(256), 0, stream>>>(qb, kb, sc);
  pv_gemm<<<dim3(4, 32, 4), dim3(256), 0, stream>>>(sc, vtb, out);
}

// Round 19
// 105.954 us; speedup vs baseline: 1.0486x; 1.0486x over previous
//
#include <hip/hip_runtime.h>
#include <math.h>

// Self-attention: B=4, S=2048, E=1024, D=512, fp32 in/out, bf16 MFMA internally.
// R19: exact revert to R17 (best measured, 106.1us). R18's T5 setprio was -5us:
//      our single-barrier counted-vmcnt loop is block-lockstep (no wave
//      role-split), so priority boost starved staging waves (m190 regime).

typedef __attribute__((ext_vector_type(4))) float f32x4;
typedef __attribute__((ext_vector_type(16))) float f32x16;
typedef __attribute__((ext_vector_type(8))) short bf16x8;     // 8 bf16 = 4 VGPRs
typedef __attribute__((ext_vector_type(8))) unsigned short u16x8;

#define B_ 4
#define S_ 2048
#define E_ 1024
#define D_ 512

__device__ __forceinline__ unsigned short f2bf(float f) {
  unsigned u = __float_as_uint(f);
  u += 0x7fffu + ((u >> 16) & 1u);   // round-to-nearest-even
  return (unsigned short)(u >> 16);
}

__device__ __forceinline__ float bf2f(unsigned short h) {
  return __uint_as_float(((unsigned)h) << 16);
}

template<int N> __device__ __forceinline__ void wait_vm() {
  if constexpr (N == 0)      asm volatile("s_waitcnt vmcnt(0)" ::: "memory");
  else if constexpr (N == 3) asm volatile("s_waitcnt vmcnt(3)" ::: "memory");
  else if constexpr (N == 4) asm volatile("s_waitcnt vmcnt(4)" ::: "memory");
  else if constexpr (N == 6) asm volatile("s_waitcnt vmcnt(6)" ::: "memory");
  else static_assert(N != N, "unsupported vmcnt");
}

// ---- BK=32 staged GEMM core (qkv) ----
// LDS tile ROWS x 32 bf16; 16B granule g of row r at slot g ^ ((r>>1)&3).

template<int ROWS, int NTHR>
__device__ __forceinline__ void stage_tile32(const unsigned short* __restrict__ g, long ld,
                                             long rowBase, int kBase,
                                             unsigned short* lds, int tid) {
  constexpr int CALLS = (ROWS * 64) / (NTHR * 16);
  #pragma unroll
  for (int i = 0; i < CALLS; ++i) {
    int idx = i * NTHR + tid;
    int row = idx >> 2, cc = idx & 3;
    int src_g = cc ^ ((row >> 1) & 3);          // pre-swizzled global granule
    __builtin_amdgcn_global_load_lds(
      (const __attribute__((address_space(1))) void*)(g + (rowBase + row) * ld + kBase + src_g * 8),
      (__attribute__((address_space(3))) void*)(lds + idx * 8),
      16, 0, 0);
  }
}

// A frag for 32x32x16: lane reads A[row = lane&31][k = (lane>>5)*8 + 0..7].
template<int MT, int NTT>
__device__ __forceinline__ void compute_tile32(const unsigned short* As, const unsigned short* Bs,
                                               int a_row0, int b_row0, int lane,
                                               f32x16 (&acc)[MT][NTT]) {
  int lr = lane & 31, lhalf = lane >> 5;
  int p = (lr >> 1) & 3;                        // (row>>1)&3 with row0 % 32 == 0
  #pragma unroll
  for (int ki = 0; ki < 2; ++ki) {
    int slot = ((ki * 2 + lhalf) ^ p) * 8;      // swizzled granule offset (halfwords)
    bf16x8 af[MT], bf[NTT];
    #pragma unroll
    for (int mt = 0; mt < MT; ++mt)
      af[mt] = *(const bf16x8*)(As + (a_row0 + mt * 32 + lr) * 32 + slot);
    #pragma unroll
    for (int nt = 0; nt < NTT; ++nt)
      bf[nt] = *(const bf16x8*)(Bs + (b_row0 + nt * 32 + lr) * 32 + slot);
    #pragma unroll
    for (int mt = 0; mt < MT; ++mt)
      #pragma unroll
      for (int nt = 0; nt < NTT; ++nt)
        acc[mt][nt] = __builtin_amdgcn_mfma_f32_32x32x16_bf16(af[mt], bf[nt], acc[mt][nt], 0, 0, 0);
  }
}

// 3-buffer pipeline, one barrier per K-step, counted vmcnt (never 0 in-loop).
template<int AROWS, int BROWS, int NTHR, int MT, int NTT>
__device__ __forceinline__ void mainloop32(
    const unsigned short* __restrict__ A, long lda, long rowA,
    const unsigned short* __restrict__ Bt, long ldb, long rowB,
    int nsteps, unsigned short* AsBuf, unsigned short* BsBuf,
    int tid, int lane, int a_row0, int b_row0, f32x16 (&acc)[MT][NTT]) {
  constexpr int ASZ = AROWS * 32, BSZ = BROWS * 32;
  constexpr int LPS = (AROWS * 64) / (NTHR * 16) + (BROWS * 64) / (NTHR * 16);
  unsigned short *a0 = AsBuf, *a1 = AsBuf + ASZ, *a2 = AsBuf + 2 * ASZ;
  unsigned short *b0 = BsBuf, *b1 = BsBuf + BSZ, *b2 = BsBuf + 2 * BSZ;
  stage_tile32<AROWS, NTHR>(A, lda, rowA, 0, a0, tid);
  stage_tile32<BROWS, NTHR>(Bt, ldb, rowB, 0, b0, tid);
  if (nsteps > 1) {
    stage_tile32<AROWS, NTHR>(A, lda, rowA, 32, a1, tid);
    stage_tile32<BROWS, NTHR>(Bt, ldb, rowB, 32, b1, tid);
  }
  for (int t = 0; t < nsteps; ++t) {
    if (t < nsteps - 1) wait_vm<LPS>(); else wait_vm<0>();
    __builtin_amdgcn_s_barrier();
    __builtin_amdgcn_sched_barrier(0);
    compute_tile32<MT, NTT>(a0, b0, a_row0, b_row0, lane, acc);
    if (t + 2 < nsteps) {
      stage_tile32<AROWS, NTHR>(A, lda, rowA, (t + 2) * 32, a2, tid);
      stage_tile32<BROWS, NTHR>(Bt, ldb, rowB, (t + 2) * 32, b2, tid);
    }
    unsigned short* ta = a0; a0 = a1; a1 = a2; a2 = ta;
    unsigned short* tb = b0; b0 = b1; b1 = b2; b2 = tb;
  }
}

// ---- BK=64 machinery (scores, pv): ROWS x 64 bf16 tiles, slot = g ^ (row&7) ----

template<int ROWS, int NTHR>
__device__ __forceinline__ void stage_tile64(const unsigned short* __restrict__ g, long ld,
                                             long rowBase, int kBase,
                                             unsigned short* lds, int tid) {
  constexpr int CALLS = (ROWS * 128) / (NTHR * 16);
  #pragma unroll
  for (int i = 0; i < CALLS; ++i) {
    int idx = i * NTHR + tid;
    int row = idx >> 3, cc = idx & 7;
    int src_g = cc ^ (row & 7);                 // pre-swizzled global granule
    __builtin_amdgcn_global_load_lds(
      (const __attribute__((address_space(1))) void*)(g + (rowBase + row) * ld + kBase + src_g * 8),
      (__attribute__((address_space(3))) void*)(lds + idx * 8),
      16, 0, 0);
  }
}

// 64x128 tile, wave (wm,wn) does 32m x 64n, BK=64 (ki=0..3); optional
// accl = MFMA(A-frag, ones) row-sum accumulation (pv's l).
template<bool WITH_L>
__device__ __forceinline__ void compute64(const unsigned short* As, const unsigned short* Bs,
                                          int a_row0, int b_row0, int lane, bf16x8 ones,
                                          f32x16 (&acc)[2], f32x16& accl) {
  int lr = lane & 31, lhalf = lane >> 5;
  int p = lr & 7;
  #pragma unroll
  for (int ki = 0; ki < 4; ++ki) {
    int slot = ((ki * 2 + lhalf) ^ p) * 8;      // granule within 64-col row
    bf16x8 af  = *(const bf16x8*)(As + (a_row0 + lr) * 64 + slot);
    bf16x8 bf0 = *(const bf16x8*)(Bs + (b_row0 + lr) * 64 + slot);
    bf16x8 bf1 = *(const bf16x8*)(Bs + (b_row0 + 32 + lr) * 64 + slot);
    if constexpr (WITH_L)
      accl = __builtin_amdgcn_mfma_f32_32x32x16_bf16(af, ones, accl, 0, 0, 0);
    acc[0] = __builtin_amdgcn_mfma_f32_32x32x16_bf16(af, bf0, acc[0], 0, 0, 0);
    acc[1] = __builtin_amdgcn_mfma_f32_32x32x16_bf16(af, bf1, acc[1], 0, 0, 0);
  }
}

// 3 buffers, BK=64, LPS = 2(A) + 4(B) = 6, counted vmcnt (never 0 in-loop).
template<bool WITH_L>
__device__ __forceinline__ void mainloop64(
    const unsigned short* __restrict__ A, long lda, long rowA,
    const unsigned short* __restrict__ Bt, long ldb, long rowB,
    int nsteps, unsigned short (*As)[64 * 64], unsigned short (*Bs)[128 * 64],
    int tid, int lane, int a_row0, int b_row0,
    f32x16 (&acc)[2], f32x16& accl) {
  bf16x8 ones;
  #pragma unroll
  for (int j = 0; j < 8; ++j) ones[j] = (short)0x3F80;   // bf16 1.0
  stage_tile64<64, 256>(A, lda, rowA, 0, As[0], tid);
  stage_tile64<128, 256>(Bt, ldb, rowB, 0, Bs[0], tid);
  if (nsteps > 1) {
    stage_tile64<64, 256>(A, lda, rowA, 64, As[1], tid);
    stage_tile64<128, 256>(Bt, ldb, rowB, 64, Bs[1], tid);
  }
  int cur = 0;
  for (int t = 0; t < nsteps; ++t) {
    if (t < nsteps - 1) wait_vm<6>(); else wait_vm<0>();
    __builtin_amdgcn_s_barrier();
    __builtin_amdgcn_sched_barrier(0);
    compute64<WITH_L>(As[cur], Bs[cur], a_row0, b_row0, lane, ones, acc, accl);
    if (t + 2 < nsteps) {
      int nxt = (cur + 2) % 3;
      stage_tile64<64, 256>(A, lda, rowA, (t + 2) * 64, As[nxt], tid);
      stage_tile64<128, 256>(Bt, ldb, rowB, (t + 2) * 64, Bs[nxt], tid);
    }
    cur = (cur + 1) % 3;
  }
}

// ---- kernels ----

// part 1 (blocks [0,4096)): x f32 -> xb bf16, coalesced.
// part 2 (blocks [4096,4480)): wbT[n][k] = w[k][d] via 64x64 LDS transpose.
__global__ __launch_bounds__(256) void prep(const float* __restrict__ x,
                                            const float* __restrict__ wq,
                                            const float* __restrict__ wk,
                                            const float* __restrict__ wv,
                                            unsigned short* __restrict__ xb,
                                            unsigned short* __restrict__ wbT) {
  int bx = blockIdx.x;
  if (bx < 4096) {
    long i = (long)bx * 256 + threadIdx.x;  // 8 elems per thread
    f32x4 a = ((const f32x4*)x)[2 * i];
    f32x4 b = ((const f32x4*)x)[2 * i + 1];
    u16x8 o;
    #pragma unroll
    for (int j = 0; j < 4; ++j) { o[j] = f2bf(a[j]); o[4 + j] = f2bf(b[j]); }
    ((u16x8*)xb)[i] = o;
  } else {
    int t = bx - 4096;              // 0..383 = 3 w x 16 kblk x 8 dblk
    int widx = t >> 7;
    int rem  = t & 127;
    int kblk = rem >> 3, dblk = rem & 7;
    const float* w = (widx == 0) ? wq : ((widx == 1) ? wk : wv);
    __shared__ float ls[64][65];    // pad 65: transpose reads 2-way max
    int tid = threadIdx.x;
    int r = tid >> 2, c16 = (tid & 3) * 16;
    const float* src = w + (long)(kblk * 64 + r) * 512 + dblk * 64 + c16;
    #pragma unroll
    for (int j = 0; j < 4; ++j) {
      f32x4 v = *(const f32x4*)(src + j * 4);
      ls[r][c16 + j * 4 + 0] = v[0];
      ls[r][c16 + j * 4 + 1] = v[1];
      ls[r][c16 + j * 4 + 2] = v[2];
      ls[r][c16 + j * 4 + 3] = v[3];
    }
    __syncthreads();
    int nl = tid >> 2;              // local n (= d) row 0..63
    unsigned short* dst = wbT + (long)(widx * 512 + dblk * 64 + nl) * 1024
                              + kblk * 64 + c16;
    u16x8 o0, o1;
    #pragma unroll
    for (int j = 0; j < 8; ++j) {
      o0[j] = f2bf(ls[c16 + j][nl]);
      o1[j] = f2bf(ls[c16 + 8 + j][nl]);
    }
    *(u16x8*)dst = o0;
    *(u16x8*)(dst + 8) = o1;
  }
}

__global__ __launch_bounds__(256, 3) void qkv_gemm(
    const unsigned short* __restrict__ xb, const unsigned short* __restrict__ wbT,
    const float* __restrict__ bq, const float* __restrict__ bk, const float* __restrict__ bv,
    unsigned short* __restrict__ qb, unsigned short* __restrict__ kb,
    unsigned short* __restrict__ vtb) {
  __shared__ unsigned short lds[24576];   // 48 KB: A bufs [0,12288), B bufs [12288,24576)
  unsigned short* AsB = lds;
  unsigned short* BsB = lds + 3 * 4096;
  int tid = threadIdx.x, wave = tid >> 6, lane = tid & 63;
  int wm = wave >> 1, wn = wave & 1;
  // XCD-aware bijective swizzle: 768 wgs, 96 per XCD chunk (768 % 8 == 0).
  int wg = blockIdx.x;
  int swz = (wg & 7) * 96 + (wg >> 3);
  int nb = swz % 12, mb = swz / 12;                // n fastest -> chunk shares A panel
  long rowA = (long)mb * 128, rowB = (long)nb * 128;
  f32x16 acc[2][2] = {};
  mainloop32<128, 128, 256, 2, 2>(xb, E_, rowA, wbT, E_, rowB, E_ / 32,
                                  AsB, BsB, tid, lane, wm * 64, wn * 64, acc);
  int lc = lane & 31, lhi = (lane >> 5) * 4;
  if (rowB < 1024) {
    // q / k panels: direct [m][d] bf16 store with bias.
    #pragma unroll
    for (int nt = 0; nt < 2; ++nt) {
      int n = (int)rowB + wn * 64 + nt * 32 + lc;
      int d = n & 511;
      float bias; unsigned short* dst;
      if (n < 512) { bias = bq[d]; dst = qb; }
      else         { bias = bk[d]; dst = kb; }
      #pragma unroll
      for (int mt = 0; mt < 2; ++mt) {
        long mbase = rowA + wm * 64 + mt * 32 + lhi;
        #pragma unroll
        for (int r = 0; r < 16; ++r) {
          long m = mbase + (r & 3) + 8 * (r >> 2);
          dst[m * D_ + d] = f2bf(acc[mt][nt][r] + bias);
        }
      }
    }
  } else {
    // v panel: bias + IN-BLOCK TRANSPOSE through LDS -> vtb[d][m] coalesced.
    __syncthreads();                       // mainloop LDS reads done
    #pragma unroll
    for (int nt = 0; nt < 2; ++nt) {
      int n_loc = wn * 64 + nt * 32 + lc;
      float bias = bv[(int)(rowB - 1024) + n_loc];
      #pragma unroll
      for (int mt = 0; mt < 2; ++mt) {
        int mb0 = wm * 64 + mt * 32 + lhi;
        #pragma unroll
        for (int r = 0; r < 16; ++r) {
          int m_loc = mb0 + (r & 3) + 8 * (r >> 2);
          lds[n_loc * 136 + m_loc] = f2bf(acc[mt][nt][r] + bias);  // pad 136 vs conflicts
        }
      }
    }
    __syncthreads();
    int d_loc = tid >> 1, hf = tid & 1;    // 128 d-rows x 2 halves of 64 m
    long d = (rowB - 1024) + d_loc;
    long bb = rowA >> 11;                  // batch (rowA is 128-aligned within 2048-blocks)
    long s0 = (rowA & 2047) + hf * 64;
    unsigned short* dstv = vtb + (bb * D_ + d) * (long)S_ + s0;
    #pragma unroll
    for (int j = 0; j < 8; ++j)
      *(u16x8*)(dstv + j * 8) = *(const u16x8*)&lds[d_loc * 136 + hf * 64 + j * 8];
  }
}

// scores+exp: 64x128 tiles on the BK=64 mainloop (8 fat steps, 3-buf,
// counted vmcnt(6), 72KB LDS, 2 blocks/CU). grid (jb=16, 32, b=4), im=31-y,
// active iff 2*jb <= im (1088 blocks). Epilogue: p = exp2(s*c) masked, bf16.
__global__ __launch_bounds__(256, 2) void scores_gemm(
    const unsigned short* __restrict__ qb, const unsigned short* __restrict__ kb,
    unsigned short* __restrict__ sc) {
  int jb = blockIdx.x, im = 31 - blockIdx.y, b = blockIdx.z;
  if (2 * jb > im) return;   // tile entirely above diagonal: never read downstream
  __shared__ unsigned short As[3][64 * 64], Bs[3][128 * 64];   // 72 KB
  int tid = threadIdx.x, wave = tid >> 6, lane = tid & 63;
  int wm = wave >> 1, wn = wave & 1;   // wave-tile 32m x 64n
  const unsigned short* A  = qb + (long)b * S_ * D_;
  const unsigned short* Bt = kb + (long)b * S_ * D_;   // k stored [s][d] == [n][k]
  long rowA = (long)im * 64, rowB = (long)jb * 128;
  f32x16 acc[2] = {};
  f32x16 accl = {};
  mainloop64<false>(A, D_, rowA, Bt, D_, rowB, D_ / 64, As, Bs, tid, lane,
                    wm * 32, wn * 64, acc, accl);
  unsigned short* po = sc + (long)b * S_ * S_;
  const float cexp = 1.4426950408889634f / 22.627416997969522f;  // log2(e)/sqrt(512)
  int lc = lane & 31, lhi = (lane >> 5) * 4;
  long mbase = rowA + wm * 32 + lhi;
  #pragma unroll
  for (int r = 0; r < 16; ++r) {
    long m = mbase + (r & 3) + 8 * (r >> 2);
    #pragma unroll
    for (int nt = 0; nt < 2; ++nt) {
      long n = rowB + wn * 64 + nt * 32 + lc;
      float p = (n <= m) ? exp2f(acc[nt][r] * cexp) : 0.f;
      po[m * S_ + n] = f2bf(p);
    }
  }
}

// PV: 64x128 tile, BK=64, chain nsteps = bm+1 <= 32, 72KB LDS -> 2 blocks/CU,
// grid (bn=4, bm=32 reversed, b=4) = 512 blocks, longest-first. l via
// ones-MFMA (accl[r]); divide on store.
__global__ __launch_bounds__(256, 2) void pv_gemm(
    const unsigned short* __restrict__ sc, const unsigned short* __restrict__ vtb,
    float* __restrict__ out) {
  int bn = blockIdx.x, bm = 31 - blockIdx.y, b = blockIdx.z;
  __shared__ unsigned short As[3][64 * 64], Bs[3][128 * 64];   // 72 KB
  int tid = threadIdx.x, wave = tid >> 6, lane = tid & 63;
  int wm = wave >> 1, wn = wave & 1;   // wave-tile 32m x 64n
  const unsigned short* A  = sc  + (long)b * S_ * S_;   // P [2048][2048]
  const unsigned short* Bt = vtb + (long)b * D_ * S_;   // V^T [512][2048]
  long rowA = (long)bm * 64, rowB = (long)bn * 128;
  int nsteps = bm + 1;
  f32x16 acc[2] = {};
  f32x16 accl = {};
  mainloop64<true>(A, S_, rowA, Bt, S_, rowB, nsteps, As, Bs, tid, lane,
                   wm * 32, wn * 64, acc, accl);
  float* oo = out + (long)b * S_ * D_;
  int lc = lane & 31, lhi = (lane >> 5) * 4;
  long mbase = rowA + wm * 32 + lhi;
  #pragma unroll
  for (int r = 0; r < 16; ++r) {
    long m = mbase + (r & 3) + 8 * (r >> 2);
    float inv = 1.f / accl[r];
    #pragma unroll
    for (int nt = 0; nt < 2; ++nt) {
      long n = rowB + wn * 64 + nt * 32 + lc;
      oo[m * D_ + n] = acc[nt][r] * inv;
    }
  }
}

extern "C" void kernel_launch(void* const* d_in, const int* in_sizes, int n_in,
                              void* d_out, int out_size, void* d_ws, size_t ws_size,
                              hipStream_t stream) {
  const float* x   = (const float*)d_in[0];
  const float* wq  = (const float*)d_in[1];
  const float* bq  = (const float*)d_in[2];
  const float* wk  = (const float*)d_in[3];
  const float* bk  = (const float*)d_in[4];
  const float* wv  = (const float*)d_in[5];
  const float* bv  = (const float*)d_in[6];
  float* out = (float*)d_out;

  // workspace layout (bytes), total ~75 MB
  char* ws = (char*)d_ws;
  unsigned short* xb  = (unsigned short*)(ws);                 // 16,777,216  x bf16 [8192][1024]
  unsigned short* wbT = (unsigned short*)(ws + 16777216);      //  3,145,728  w^T bf16 [1536][1024]
  unsigned short* qb  = (unsigned short*)(ws + 19922944);      //  8,388,608  q bf16 [8192][512]
  unsigned short* kb  = (unsigned short*)(ws + 28311552);      //  8,388,608
  unsigned short* vtb = (unsigned short*)(ws + 36700160);      //  8,388,608  v^T bf16 [4][512][2048]
  unsigned short* sc  = (unsigned short*)(ws + 45088768);      // 33,554,432  p bf16 [4][2048][2048]

  prep<<<dim3(4480), dim3(256), 0, stream>>>(x, wq, wk, wv, xb, wbT);
  qkv_gemm<<<dim3(768), dim3(256), 0, stream>>>(xb, wbT, bq, bk, bv, qb, kb, vtb);
  scores_gemm<<<dim3(16, 32, 4), dim3(256), 0, stream>>>(qb, kb, sc);
  pv_gemm<<<dim3(4, 32, 4), dim3(256), 0, stream>>>(sc, vtb, out);
}